// Round 4
// baseline (93.830 us; speedup 1.0000x reference)
//
#include <hip/hip_runtime.h>
#include <hip/hip_bf16.h>
#include <math.h>

#define C_    128
#define NQ_   8
#define NK_   32768
#define QNK_  (NQ_*NK_)
#define KT_   32
#define NBLK_ (NK_/KT_)   // 1024
#define NCH_  256         // softmax chunks of 128 cols

// ws float offsets
#define AQ_OFF     0        // [q][o] 1024
#define MINKEY_OFF 1024     // 1 uint (order-preserving float key)
#define DENOM_OFF  1040     // 8*256
#define OUTV_OFF   4096     // 256*1024
#define WSA_OFF    266240   // bf16 A-frag table: 32768 shorts (16384 floats)

typedef float f32x4 __attribute__((ext_vector_type(4)));
typedef int   i32x4 __attribute__((ext_vector_type(4)));
typedef short bf16x8 __attribute__((ext_vector_type(8)));

__device__ inline unsigned short f2bf(float f){ // prep only
  unsigned u = __float_as_uint(f);
  return (unsigned short)((u + 0x7FFFu + ((u >> 16) & 1u)) >> 16);
}
__device__ inline unsigned int pkbf(float a, float b){
  __hip_bfloat162 h = __float22bfloat162_rn(make_float2(a, b)); // v_cvt_pk_bf16_f32
  union { __hip_bfloat162 h2; unsigned int u; } cv; cv.h2 = h; return cv.u;
}
__device__ inline unsigned int fkey(float f){   // monotone float->uint
  unsigned u = __float_as_uint(f);
  return (u & 0x80000000u) ? ~u : (u | 0x80000000u);
}
__device__ inline float fkey_dec(unsigned key){
  unsigned u = (key & 0x80000000u) ? (key & 0x7FFFFFFFu) : ~key;
  return __uint_as_float(u);
}
__device__ inline int swz8(int r){ return ((r ^ (r >> 3)) & 7) << 3; }

// ---------------- prep: 17 blocks. 0..15: A-frag table. 16: Aq + atomic init.
__global__ __launch_bounds__(256) void prep_kernel(const float* __restrict__ query,
    const float* __restrict__ W1, const float* __restrict__ b1, float* __restrict__ ws){
  const int t = threadIdx.x, b = blockIdx.x;
  if (b < 16){
    unsigned int* wsa = (unsigned int*)(ws + WSA_OFF);
    for (int u = b*1024 + t; u < (b+1)*1024; u += 256){
      unsigned int pack = 0;
#pragma unroll
      for (int e2 = 0; e2 < 2; e2++){
        const int E = u*2 + e2;
        const int f = E >> 9, lane = (E >> 3) & 63, e = E & 7;
        const int w = f >> 4, r = f & 15;
        const int part = r >> 3, ks = (r >> 1) & 3, of = r & 1;
        const int o = w*32 + of*16 + (lane & 15);
        const int c = ks*32 + ((lane >> 4) << 3) + e;
        pack |= (unsigned int)f2bf(W1[o*384 + 128 + part*128 + c]) << (16*e2);
      }
      wsa[u] = pack;
    }
  } else {
    if (t == 0) *(unsigned int*)(ws + MINKEY_OFF) = 0xFFFFFFFFu;
    if (t < 128){
      const int o = t;
      float s[8];
#pragma unroll
      for (int q = 0; q < 8; q++) s[q] = b1[o];
      for (int c = 0; c < 128; c++){
        const float wv = W1[o*384 + c];
#pragma unroll
        for (int q = 0; q < 8; q++) s[q] += wv * query[c*8 + q];
      }
#pragma unroll
      for (int q = 0; q < 8; q++) ws[AQ_OFF + q*128 + o] = s[q];
    }
  }
}

// ---------------- staging (fp32 global -> swizzled bf16 LDS [kl][c]) ----------
template<bool NT>
__device__ inline void stage_load(const float* __restrict__ src, size_t rstride,
                                  int scp, int skl4, f32x4* ra, f32x4* rb){
#pragma unroll
  for (int i = 0; i < 2; i++){
    const float* pa = src + (size_t)(2*scp + 64*i)*rstride + skl4;
    const float* pb = pa + rstride;
    if (NT){ ra[i] = __builtin_nontemporal_load((const f32x4*)pa);
             rb[i] = __builtin_nontemporal_load((const f32x4*)pb); }
    else   { ra[i] = *(const f32x4*)pa; rb[i] = *(const f32x4*)pb; }
  }
}
__device__ inline void stage_write(unsigned short* __restrict__ lds,
                                   int scp, int skl4, const f32x4* ra, const f32x4* rb){
#pragma unroll
  for (int i = 0; i < 2; i++){
    const int c = 2*scp + 64*i;
#pragma unroll
    for (int j = 0; j < 4; j++){
      const int kl = skl4 + j;
      const int idx = (kl*128 + c) ^ swz8(kl);
      *(unsigned int*)&lds[idx] = pkbf(ra[i][j], rb[i][j]);
    }
  }
}
__device__ inline bf16x8 frag_read(const unsigned short* __restrict__ lds,
                                   int cf, int ks, int g, int li){
  const int row = (cf << 4) + li;
  const int idx = (row << 7) + (((ks << 5) + (g << 3)) ^ swz8(row));
  return *(const bf16x8*)&lds[idx];
}

// ---------------- scores: 1 barrier/q-iter, deferred epilogue ----------------
__global__ __launch_bounds__(256, 3) void scores_kernel(
    const float* __restrict__ keys, const float* __restrict__ dist,
    const float* __restrict__ W2, const float* __restrict__ b2p,
    float* __restrict__ ws, float* __restrict__ scores)
{
  __shared__ unsigned short k_lds[KT_*128];      // 8KB
  __shared__ unsigned short d_lds[3][KT_*128];   // 24KB
  __shared__ float aq_lds[NQ_*128];              // 4KB
  __shared__ float red[4][256];                  // 4KB

  const int t = threadIdx.x, w = t >> 6, l = t & 63;
  const int g = l >> 4, li = l & 15;
  const int blk = blockIdx.x, k0 = blk * KT_;
  const int o0 = w * 32;

  const bf16x8* wsa8 = (const bf16x8*)(ws + WSA_OFF);
  // dist-part A fragments: resident for the whole kernel (32 VGPRs)
  bf16x8 afr_d[8];
#pragma unroll
  for (int f = 0; f < 8; f++) afr_d[f] = wsa8[(w*16 + 8 + f)*64 + l];

  const f32x4 w2v0 = *(const f32x4*)&W2[o0 + (g<<2)];
  const f32x4 w2v1 = *(const f32x4*)&W2[o0 + 16 + (g<<2)];
  const float b2v = b2p[0];

  for (int i = t; i < NQ_*128; i += 256) aq_lds[i] = ws[AQ_OFF + i];

  const int skl4 = (t & 7) * 4;
  const int scp  = t >> 3;

  // prologue: issue all loads, then write
  f32x4 ka[2], kb[2], a0[2], b0[2], a1[2], b1[2], ra[2], rb[2];
  stage_load<false>(keys + k0, NK_, scp, skl4, ka, kb);
  stage_load<true >(dist + k0,             QNK_, scp, skl4, a0, b0);  // q=0
  stage_load<true >(dist + (size_t)1*NK_ + k0, QNK_, scp, skl4, a1, b1);  // q=1
  stage_load<true >(dist + (size_t)2*NK_ + k0, QNK_, scp, skl4, ra, rb);  // q=2 (regs)
  stage_write(k_lds,    scp, skl4, ka, kb);
  stage_write(d_lds[0], scp, skl4, a0, b0);
  stage_write(d_lds[1], scp, skl4, a1, b1);
  __syncthreads();

  // Bk accumulators via transient keys-part A frags
  f32x4 bk[2][2];
#pragma unroll
  for (int cf = 0; cf < 2; cf++)
#pragma unroll
    for (int of = 0; of < 2; of++){ f32x4 z = {0.f,0.f,0.f,0.f}; bk[cf][of] = z; }
  {
    bf16x8 afk[8];
#pragma unroll
    for (int f = 0; f < 8; f++) afk[f] = wsa8[(w*16 + f)*64 + l];
#pragma unroll
    for (int ks = 0; ks < 4; ks++){
#pragma unroll
      for (int cf = 0; cf < 2; cf++){
        const bf16x8 b = frag_read(k_lds, cf, ks, g, li);
        bk[cf][0] = __builtin_amdgcn_mfma_f32_16x16x32_bf16(afk[ks*2+0], b, bk[cf][0], 0,0,0);
        bk[cf][1] = __builtin_amdgcn_mfma_f32_16x16x32_bf16(afk[ks*2+1], b, bk[cf][1], 0,0,0);
      }
    }
  }

  float ps[8][2];
#pragma unroll
  for (int q = 0; q < NQ_; q++){
    if (q <= 5) stage_write(d_lds[(q+2)%3], scp, skl4, ra, rb);   // tile q+2
    if (q <= 4) stage_load<true>(dist + (size_t)(q+3)*NK_ + k0, QNK_, scp, skl4, ra, rb);

    const unsigned short* db = d_lds[q % 3];
    f32x4 acc[2][2];
#pragma unroll
    for (int cf = 0; cf < 2; cf++)
#pragma unroll
      for (int of = 0; of < 2; of++) acc[cf][of] = bk[cf][of];
#pragma unroll
    for (int ks = 0; ks < 4; ks++){
#pragma unroll
      for (int cf = 0; cf < 2; cf++){
        const bf16x8 b = frag_read(db, cf, ks, g, li);
        acc[cf][0] = __builtin_amdgcn_mfma_f32_16x16x32_bf16(afr_d[ks*2+0], b, acc[cf][0], 0,0,0);
        acc[cf][1] = __builtin_amdgcn_mfma_f32_16x16x32_bf16(afr_d[ks*2+1], b, acc[cf][1], 0,0,0);
      }
    }

    const f32x4 aqv0 = *(const f32x4*)&aq_lds[q*128 + o0 + (g<<2)];
    const f32x4 aqv1 = *(const f32x4*)&aq_lds[q*128 + o0 + 16 + (g<<2)];
#pragma unroll
    for (int cf = 0; cf < 2; cf++){
      float s = 0.f;
#pragma unroll
      for (int r = 0; r < 4; r++){
        s += w2v0[r] * fmaxf(acc[cf][0][r] + aqv0[r], 0.f);
        s += w2v1[r] * fmaxf(acc[cf][1][r] + aqv1[r], 0.f);
      }
      s += __shfl_xor(s, 16, 64);
      s += __shfl_xor(s, 32, 64);
      ps[q][cf] = s;
    }
    __syncthreads();   // all waves done reading d_lds[q%3]; buffer rotation safe
  }

  // deferred cross-wave reduction
  if (g == 0){
#pragma unroll
    for (int q = 0; q < NQ_; q++){
      red[w][q*32 + li]      = ps[q][0];
      red[w][q*32 + 16 + li] = ps[q][1];
    }
  }
  __syncthreads();

  {
    const int q = t >> 5, col = t & 31;
    const float s = b2v + red[0][t] + red[1][t] + red[2][t] + red[3][t];
    __builtin_nontemporal_store(s, &scores[(size_t)q*NK_ + k0 + col]);
    float m = s;
#pragma unroll
    for (int off = 32; off > 0; off >>= 1) m = fminf(m, __shfl_xor(m, off, 64));
    if (l == 0) atomicMin((unsigned int*)(ws + MINKEY_OFF), fkey(m));
  }
}

// ---------------- softmax + PV partials ----------------
__global__ __launch_bounds__(256) void softmax_pv_kernel(
    const float* __restrict__ value, const int* __restrict__ mask,
    float* __restrict__ scores, float* __restrict__ ws)
{
  __shared__ float v_lds[128*128];    // XOR-swizzled [d][k]
  __shared__ __align__(16) float e_lds[8][128];
  __shared__ float wsum[8];
  const int t = threadIdx.x, bid = blockIdx.x, k0 = bid*128;
  const float floorv = fkey_dec(*(const unsigned int*)(ws + MINKEY_OFF)) - 20.0f;

  for (int i = t; i < 4096; i += 256){
    const int d = i >> 5, k4 = (i & 31)*4;
    const f32x4 v = __builtin_nontemporal_load((const f32x4*)&value[(size_t)d*NK_ + k0 + k4]);
    const int dw = (d*128 + k4) ^ ((d & 31) << 2);
    *(f32x4*)&v_lds[dw] = v;
  }

  {
    const int q = t >> 5, kk = (t & 31)*4;
    const size_t gi = (size_t)q*NK_ + k0 + kk;
    const f32x4 s4 = *(const f32x4*)&scores[gi];
    const i32x4 m4 = *(const i32x4*)&mask[gi];
    f32x4 sf, e;
#pragma unroll
    for (int j = 0; j < 4; j++){
      sf[j] = m4[j] ? s4[j] : s4[j] + floorv;
      e[j]  = __expf(sf[j]);
    }
    __builtin_nontemporal_store(sf, (f32x4*)&scores[gi]);   // final masked scores
    *(f32x4*)&e_lds[q][kk] = e;
    float es = e[0] + e[1] + e[2] + e[3];
#pragma unroll
    for (int off = 16; off > 0; off >>= 1) es += __shfl_xor(es, off, 64);
    if ((t & 31) == 0) wsum[q] = es;
  }
  __syncthreads();
  if (t < 8) ws[DENOM_OFF + t*NCH_ + bid] = wsum[t];

  const int d = t & 127, qb = (t >> 7)*4;
  f32x4 acc = {0.f,0.f,0.f,0.f};
#pragma unroll 8
  for (int k4 = 0; k4 < 128; k4 += 4){
    const int dw = (d*128 + k4) ^ ((d & 31) << 2);
    const f32x4 v  = *(const f32x4*)&v_lds[dw];
    const f32x4 e0 = *(const f32x4*)&e_lds[qb+0][k4];
    const f32x4 e1 = *(const f32x4*)&e_lds[qb+1][k4];
    const f32x4 e2 = *(const f32x4*)&e_lds[qb+2][k4];
    const f32x4 e3 = *(const f32x4*)&e_lds[qb+3][k4];
#pragma unroll
    for (int j = 0; j < 4; j++){
      acc[0] += v[j]*e0[j]; acc[1] += v[j]*e1[j];
      acc[2] += v[j]*e2[j]; acc[3] += v[j]*e3[j];
    }
  }
#pragma unroll
  for (int j = 0; j < 4; j++) ws[OUTV_OFF + (size_t)bid*1024 + d*8 + qb + j] = acc[j];
}

// ---------------- finalize: 32 blocks, coalesced chunk reduce ----------------
__global__ __launch_bounds__(256) void finalize_kernel(const float* __restrict__ ws,
    float* __restrict__ out){
  __shared__ float dsum[8];
  __shared__ float red[8][32];
  const int t = threadIdx.x, bid = blockIdx.x;

  if (t < 64){
    const int q = t >> 3, i = t & 7;
    float s = 0.f;
    for (int j = 0; j < 32; j++) s += ws[DENOM_OFF + q*NCH_ + i + 8*j];
#pragma unroll
    for (int off = 4; off > 0; off >>= 1) s += __shfl_xor(s, off, 64);
    if (i == 0) dsum[q] = s;
  }

  const int ol = t & 31, part = t >> 5;
  float s = 0.f;
  for (int j = 0; j < 32; j++)
    s += ws[OUTV_OFF + (size_t)(part + 8*j)*1024 + bid*32 + ol];
  red[part][ol] = s;
  __syncthreads();

  if (t < 32){
    float a = 0.f;
#pragma unroll
    for (int p = 0; p < 8; p++) a += red[p][t];
    const int o = bid*32 + t;
    out[o] = a / dsum[o & 7];
  }
}

extern "C" void kernel_launch(void* const* d_in, const int* in_sizes, int n_in,
                              void* d_out, int out_size, void* d_ws, size_t ws_size,
                              hipStream_t stream){
  const float* query=(const float*)d_in[0];
  const float* keys =(const float*)d_in[1];
  const float* value=(const float*)d_in[2];
  const float* dist =(const float*)d_in[3];
  const int*   mask =(const int*)d_in[4];
  const float* W1   =(const float*)d_in[5];
  const float* b1   =(const float*)d_in[6];
  const float* W2   =(const float*)d_in[7];
  const float* b2   =(const float*)d_in[8];
  float* out=(float*)d_out;
  float* scores=out+1024;
  float* ws=(float*)d_ws;

  prep_kernel      <<<17,256,0,stream>>>(query,W1,b1,ws);
  scores_kernel    <<<NBLK_,256,0,stream>>>(keys,dist,W2,b2,ws,scores);
  softmax_pv_kernel<<<NCH_,256,0,stream>>>(value,mask,scores,ws);
  finalize_kernel  <<<32,256,0,stream>>>(ws,out);
}

// Round 5
// 65.692 us; speedup vs baseline: 1.4283x; 1.4283x over previous
//
#include <hip/hip_runtime.h>
#include <hip/hip_bf16.h>
#include <math.h>

#define C_    128
#define NQ_   8
#define NK_   32768
#define QNK_  (NQ_*NK_)
#define KW_   16          // cols per wave
#define KTB_  64          // cols per block (4 waves)
#define NSB_  512         // scores blocks
#define NCH_  256         // softmax chunks of 128 cols

// ws float offsets
#define AQ_OFF     0        // [q][o] 1024
#define MINKEY_OFF 1024     // 1 uint (order-preserving float key)
#define DENOM_OFF  1040     // 8*256
#define OUTV_OFF   4096     // 256*1024
#define WSA_OFF    266240   // bf16 A-frag table: 64 frags x 64 lanes x 8 bf16

typedef float f32x4 __attribute__((ext_vector_type(4)));
typedef int   i32x4 __attribute__((ext_vector_type(4)));
typedef short bf16x8 __attribute__((ext_vector_type(8)));

__device__ inline unsigned short f2bf(float f){ // prep only
  unsigned u = __float_as_uint(f);
  return (unsigned short)((u + 0x7FFFu + ((u >> 16) & 1u)) >> 16);
}
__device__ inline unsigned int pkbf(float a, float b){
  __hip_bfloat162 h = __float22bfloat162_rn(make_float2(a, b)); // v_cvt_pk_bf16_f32
  union { __hip_bfloat162 h2; unsigned int u; } cv; cv.h2 = h; return cv.u;
}
__device__ inline unsigned int fkey(float f){   // monotone float->uint
  unsigned u = __float_as_uint(f);
  return (u & 0x80000000u) ? ~u : (u | 0x80000000u);
}
__device__ inline float fkey_dec(unsigned key){
  unsigned u = (key & 0x80000000u) ? (key & 0x7FFFFFFFu) : ~key;
  return __uint_as_float(u);
}
__device__ inline int swz8(int r){ return ((r ^ (r >> 3)) & 7) << 3; }

// ---------------- prep: 17 blocks. 0..15: A-frag table. 16: Aq + atomic init.
// Table layout: frag F = w*16 + part*8 + ks*2 + of (w=o-quarter, part 0=keys 1=dist)
// element: [F][lane][e] = W1[o=w*32+of*16+(lane&15)][128 + part*128 + ks*32 + (lane>>4)*8 + e]
__global__ __launch_bounds__(256) void prep_kernel(const float* __restrict__ query,
    const float* __restrict__ W1, const float* __restrict__ b1, float* __restrict__ ws){
  const int t = threadIdx.x, b = blockIdx.x;
  if (b < 16){
    unsigned int* wsa = (unsigned int*)(ws + WSA_OFF);
    for (int u = b*1024 + t; u < (b+1)*1024; u += 256){
      unsigned int pack = 0;
#pragma unroll
      for (int e2 = 0; e2 < 2; e2++){
        const int E = u*2 + e2;
        const int f = E >> 9, lane = (E >> 3) & 63, e = E & 7;
        const int w = f >> 4, r = f & 15;
        const int part = r >> 3, ks = (r >> 1) & 3, of = r & 1;
        const int o = w*32 + of*16 + (lane & 15);
        const int c = ks*32 + ((lane >> 4) << 3) + e;
        pack |= (unsigned int)f2bf(W1[o*384 + 128 + part*128 + c]) << (16*e2);
      }
      wsa[u] = pack;
    }
  } else {
    if (t == 0) *(unsigned int*)(ws + MINKEY_OFF) = 0xFFFFFFFFu;
    if (t < 128){
      const int o = t;
      float s[8];
#pragma unroll
      for (int q = 0; q < 8; q++) s[q] = b1[o];
      for (int c = 0; c < 128; c++){
        const float wv = W1[o*384 + c];
#pragma unroll
        for (int q = 0; q < 8; q++) s[q] += wv * query[c*8 + q];
      }
#pragma unroll
      for (int q = 0; q < 8; q++) ws[AQ_OFF + q*128 + o] = s[q];
    }
  }
}

// ---- per-wave 16-col staging: fp32 [c][k] global -> swizzled bf16 LDS [kl][c] ----
__device__ inline void stage16_load(const float* __restrict__ src, size_t rstride,
                                    int l, f32x4* ra, f32x4* rb){
  const int skl = (l & 3) * 4;
  const int c2  = (l >> 2) * 2;
#pragma unroll
  for (int p = 0; p < 4; p++){
    const float* pa = src + (size_t)(p*32 + c2)*rstride + skl;
    ra[p] = __builtin_nontemporal_load((const f32x4*)pa);
    rb[p] = __builtin_nontemporal_load((const f32x4*)(pa + rstride));
  }
}
__device__ inline void stage16_write(unsigned short* __restrict__ lds,
                                     int l, const f32x4* ra, const f32x4* rb){
  const int skl = (l & 3) * 4;
  const int c2  = (l >> 2) * 2;
#pragma unroll
  for (int p = 0; p < 4; p++){
    const int c = p*32 + c2;
#pragma unroll
    for (int j = 0; j < 4; j++){
      const int kl = skl + j;
      const int idx = (kl*128 + c) ^ swz8(kl);
      *(unsigned int*)&lds[idx] = pkbf(ra[p][j], rb[p][j]);
    }
  }
}
__device__ inline bf16x8 frag16_read(const unsigned short* __restrict__ lds,
                                     int ks, int g, int li){
  const int idx = (li << 7) + (((ks << 5) + (g << 3)) ^ swz8(li));
  return *(const bf16x8*)&lds[idx];
}

// ---------------- scores: wave-private columns, zero barriers in main loop ----
__global__ __launch_bounds__(256, 2) void scores_kernel(
    const float* __restrict__ keys, const float* __restrict__ dist,
    const float* __restrict__ W2, const float* __restrict__ b2p,
    float* __restrict__ ws, float* __restrict__ scores)
{
  __shared__ unsigned short a_lds[32*512];     // 32 frag slots x 64 lanes x 8 bf16 = 32KB
  __shared__ unsigned short d_lds[4][KW_*128]; // per-wave 4KB
  __shared__ float aq_lds[NQ_*128];            // 4KB
  __shared__ float w2_lds[128];
  __shared__ float minred[4];

  const int t = threadIdx.x, w = t >> 6, l = t & 63;
  const int g = l >> 4, li = l & 15;
  const int blk = blockIdx.x;
  const int k0w = blk*KTB_ + w*KW_;
  unsigned short* dw = d_lds[w];

  // cooperative: W1-keys frag slots (slot s=(w',ks,of): src frag F=(s>>3)*16+(s&7))
  const unsigned int* wsaU = (const unsigned int*)(ws + WSA_OFF);
  unsigned int* aU = (unsigned int*)a_lds;
  for (int i = t; i < 8192; i += 256){
    const int s = i >> 8, r = i & 255;
    aU[i] = wsaU[((s >> 3)*16 + (s & 7))*256 + r];
  }
  for (int i = t; i < NQ_*128; i += 256) aq_lds[i] = ws[AQ_OFF + i];
  if (t < 128) w2_lds[t] = W2[t];

  // wave-private: stage keys tile, then issue dist q=0 loads
  f32x4 rA[4], rB[4], rC[4], rD[4];
  stage16_load(keys + k0w, NK_, l, rA, rB);
  stage16_write(dw, l, rA, rB);
  stage16_load(dist + k0w, QNK_, l, rA, rB);   // q=0 (regs, consumed in loop)
  __syncthreads();                             // a_lds(W1k), aq, w2 ready

  // Bk accumulators (keys part), reused for all 8 q
  f32x4 bk[8];
#pragma unroll
  for (int f = 0; f < 8; f++){ f32x4 z = {0.f,0.f,0.f,0.f}; bk[f] = z; }
#pragma unroll
  for (int ks = 0; ks < 4; ks++){
    const bf16x8 bfr = frag16_read(dw, ks, g, li);
#pragma unroll
    for (int of8 = 0; of8 < 8; of8++){
      const int s = (of8 >> 1)*8 + ks*2 + (of8 & 1);
      const bf16x8 a = *(const bf16x8*)&a_lds[s*512 + l*8];
      bk[of8] = __builtin_amdgcn_mfma_f32_16x16x32_bf16(a, bfr, bk[of8], 0,0,0);
    }
  }
  __syncthreads();                             // all waves done with W1k slots

  // cooperative: overwrite slots with W1-dist frags (F=(s>>3)*16+8+(s&7))
  for (int i = t; i < 8192; i += 256){
    const int s = i >> 8, r = i & 255;
    aU[i] = wsaU[((s >> 3)*16 + 8 + (s & 7))*256 + r];
  }
  __syncthreads();                             // a_lds(W1d) ready

  const float b2v = b2p[0];
  float minv = INFINITY;

#define SCORE_ITER(Q, RA, RB, RA2, RB2)                                          \
  {                                                                              \
    if ((Q) < 7) stage16_load(dist + (size_t)((Q)+1)*NK_ + k0w, QNK_, l, RA2, RB2); \
    stage16_write(dw, l, RA, RB);                                                \
    f32x4 acc[8];                                                                \
    _Pragma("unroll")                                                            \
    for (int f = 0; f < 8; f++) acc[f] = bk[f];                                  \
    _Pragma("unroll")                                                            \
    for (int ks = 0; ks < 4; ks++){                                              \
      const bf16x8 bfr = frag16_read(dw, ks, g, li);                             \
      _Pragma("unroll")                                                          \
      for (int of8 = 0; of8 < 8; of8++){                                         \
        const int s = (of8 >> 1)*8 + ks*2 + (of8 & 1);                           \
        const bf16x8 a = *(const bf16x8*)&a_lds[s*512 + l*8];                    \
        acc[of8] = __builtin_amdgcn_mfma_f32_16x16x32_bf16(a, bfr, acc[of8], 0,0,0); \
      }                                                                          \
    }                                                                            \
    float sv = 0.f;                                                              \
    _Pragma("unroll")                                                            \
    for (int of8 = 0; of8 < 8; of8++){                                           \
      const int ob = (of8 >> 1)*32 + (of8 & 1)*16 + g*4;                         \
      const f32x4 aqv = *(const f32x4*)&aq_lds[(Q)*128 + ob];                    \
      const f32x4 w2v = *(const f32x4*)&w2_lds[ob];                              \
      _Pragma("unroll")                                                          \
      for (int r = 0; r < 4; r++)                                                \
        sv += w2v[r] * fmaxf(acc[of8][r] + aqv[r], 0.f);                         \
    }                                                                            \
    sv += __shfl_xor(sv, 16, 64);                                                \
    sv += __shfl_xor(sv, 32, 64);                                                \
    sv += b2v;                                                                   \
    if (l < 16)                                                                  \
      __builtin_nontemporal_store(sv, &scores[(size_t)(Q)*NK_ + k0w + l]);       \
    minv = fminf(minv, sv);                                                      \
  }

  SCORE_ITER(0, rA, rB, rC, rD)
  SCORE_ITER(1, rC, rD, rA, rB)
  SCORE_ITER(2, rA, rB, rC, rD)
  SCORE_ITER(3, rC, rD, rA, rB)
  SCORE_ITER(4, rA, rB, rC, rD)
  SCORE_ITER(5, rC, rD, rA, rB)
  SCORE_ITER(6, rA, rB, rC, rD)
  SCORE_ITER(7, rC, rD, rA, rB)
#undef SCORE_ITER

#pragma unroll
  for (int off = 32; off > 0; off >>= 1) minv = fminf(minv, __shfl_xor(minv, off, 64));
  if (l == 0) minred[w] = minv;
  __syncthreads();
  if (t == 0){
    const float m = fminf(fminf(minred[0], minred[1]), fminf(minred[2], minred[3]));
    atomicMin((unsigned int*)(ws + MINKEY_OFF), fkey(m));
  }
}

// ---------------- softmax + PV partials ----------------
__global__ __launch_bounds__(256) void softmax_pv_kernel(
    const float* __restrict__ value, const int* __restrict__ mask,
    float* __restrict__ scores, float* __restrict__ ws)
{
  __shared__ float v_lds[128*128];    // XOR-swizzled [d][k]
  __shared__ __align__(16) float e_lds[8][128];
  __shared__ float wsum[8];
  const int t = threadIdx.x, bid = blockIdx.x, k0 = bid*128;
  const float floorv = fkey_dec(*(const unsigned int*)(ws + MINKEY_OFF)) - 20.0f;

  for (int i = t; i < 4096; i += 256){
    const int d = i >> 5, k4 = (i & 31)*4;
    const f32x4 v = __builtin_nontemporal_load((const f32x4*)&value[(size_t)d*NK_ + k0 + k4]);
    const int dw = (d*128 + k4) ^ ((d & 31) << 2);
    *(f32x4*)&v_lds[dw] = v;
  }

  {
    const int q = t >> 5, kk = (t & 31)*4;
    const size_t gi = (size_t)q*NK_ + k0 + kk;
    const f32x4 s4 = *(const f32x4*)&scores[gi];
    const i32x4 m4 = *(const i32x4*)&mask[gi];
    f32x4 sf, e;
#pragma unroll
    for (int j = 0; j < 4; j++){
      sf[j] = m4[j] ? s4[j] : s4[j] + floorv;
      e[j]  = __expf(sf[j]);
    }
    __builtin_nontemporal_store(sf, (f32x4*)&scores[gi]);   // final masked scores
    *(f32x4*)&e_lds[q][kk] = e;
    float es = e[0] + e[1] + e[2] + e[3];
#pragma unroll
    for (int off = 16; off > 0; off >>= 1) es += __shfl_xor(es, off, 64);
    if ((t & 31) == 0) wsum[q] = es;
  }
  __syncthreads();
  if (t < 8) ws[DENOM_OFF + t*NCH_ + bid] = wsum[t];

  const int d = t & 127, qb = (t >> 7)*4;
  f32x4 acc = {0.f,0.f,0.f,0.f};
#pragma unroll 8
  for (int k4 = 0; k4 < 128; k4 += 4){
    const int dw = (d*128 + k4) ^ ((d & 31) << 2);
    const f32x4 v  = *(const f32x4*)&v_lds[dw];
    const f32x4 e0 = *(const f32x4*)&e_lds[qb+0][k4];
    const f32x4 e1 = *(const f32x4*)&e_lds[qb+1][k4];
    const f32x4 e2 = *(const f32x4*)&e_lds[qb+2][k4];
    const f32x4 e3 = *(const f32x4*)&e_lds[qb+3][k4];
#pragma unroll
    for (int j = 0; j < 4; j++){
      acc[0] += v[j]*e0[j]; acc[1] += v[j]*e1[j];
      acc[2] += v[j]*e2[j]; acc[3] += v[j]*e3[j];
    }
  }
#pragma unroll
  for (int j = 0; j < 4; j++) ws[OUTV_OFF + (size_t)bid*1024 + d*8 + qb + j] = acc[j];
}

// ---------------- finalize: 32 blocks, coalesced chunk reduce ----------------
__global__ __launch_bounds__(256) void finalize_kernel(const float* __restrict__ ws,
    float* __restrict__ out){
  __shared__ float dsum[8];
  __shared__ float red[8][32];
  const int t = threadIdx.x, bid = blockIdx.x;

  if (t < 64){
    const int q = t >> 3, i = t & 7;
    float s = 0.f;
    for (int j = 0; j < 32; j++) s += ws[DENOM_OFF + q*NCH_ + i + 8*j];
#pragma unroll
    for (int off = 4; off > 0; off >>= 1) s += __shfl_xor(s, off, 64);
    if (i == 0) dsum[q] = s;
  }

  const int ol = t & 31, part = t >> 5;
  float s = 0.f;
  for (int j = 0; j < 32; j++)
    s += ws[OUTV_OFF + (size_t)(part + 8*j)*1024 + bid*32 + ol];
  red[part][ol] = s;
  __syncthreads();

  if (t < 32){
    float a = 0.f;
#pragma unroll
    for (int p = 0; p < 8; p++) a += red[p][t];
    const int o = bid*32 + t;
    out[o] = a / dsum[o & 7];
  }
}

extern "C" void kernel_launch(void* const* d_in, const int* in_sizes, int n_in,
                              void* d_out, int out_size, void* d_ws, size_t ws_size,
                              hipStream_t stream){
  const float* query=(const float*)d_in[0];
  const float* keys =(const float*)d_in[1];
  const float* value=(const float*)d_in[2];
  const float* dist =(const float*)d_in[3];
  const int*   mask =(const int*)d_in[4];
  const float* W1   =(const float*)d_in[5];
  const float* b1   =(const float*)d_in[6];
  const float* W2   =(const float*)d_in[7];
  const float* b2   =(const float*)d_in[8];
  float* out=(float*)d_out;
  float* scores=out+1024;
  float* ws=(float*)d_ws;

  prep_kernel      <<<17,256,0,stream>>>(query,W1,b1,ws);
  scores_kernel    <<<NSB_,256,0,stream>>>(keys,dist,W2,b2,ws,scores);
  softmax_pv_kernel<<<NCH_,256,0,stream>>>(value,mask,scores,ws);
  finalize_kernel  <<<32,256,0,stream>>>(ws,out);
}